// Round 26
// baseline (282.895 us; speedup 1.0000x reference)
//
#include <hip/hip_runtime.h>
#include <math.h>

#define Bn 16
#define Cn 64
#define Hn 192
#define Wn 192
#define NPIX (Bn * Cn * Hn * Wn)       // 37748736
#define NBLKS 256
#define ROWS 12
#define SLOTB (194 * 128)              // 24832 B per full-width window row-slot

typedef short bf16x8 __attribute__((ext_vector_type(8)));
typedef float f32x16 __attribute__((ext_vector_type(16)));

// A-operand fragments, contiguous per (sp, ks, mhalf): g_Mf[fi][lane][8 bf16],
// fi = (sp*4+ks)*2+mh. Lane l holds M row (l&31)+32*mh, channels (2ks+(l>>5))*8+e.
// 72 KB total -> L2-resident; compute reads it as coalesced global_load_dwordx4.
__device__ __align__(16) unsigned short g_Mf[9 * 4 * 2 * 512];
__device__ __align__(16) float g_b2[64];

static __device__ __forceinline__ unsigned short f2bf(float f) {
    union { float f; unsigned u; } x; x.f = f;
    unsigned r = x.u + 0x7fffu + ((x.u >> 16) & 1u);   // RNE
    return (unsigned short)(r >> 16);
}

__global__ void acdc_precompute(const float* __restrict__ cw, const float* __restrict__ A,
                                const float* __restrict__ D, const float* __restrict__ bias,
                                const int* __restrict__ perm) {
    __shared__ float mre[64];
    int p = blockIdx.x;      // M row = output channel 0..63
    int t = threadIdx.x;
    if (t < 64) {
        float re = 0.f;
        for (int k = 0; k < 64; ++k) {
            int a = (k * t) & 63;
            re += D[k] * cosf((float)a * 0.0981747704246810387f);  // pi/32
        }
        mre[t] = re;
    }
    __syncthreads();
    int pp = perm[p];
    int mh = p >> 5, l31 = p & 31;
    for (int k0 = t; k0 < 576; k0 += 256) {
        int sp = k0 >> 6, c = k0 & 63;
        int g = c >> 3, cil = c & 7;
        float val = 0.f;
        for (int o = 0; o < 8; ++o) {
            int oc = g * 8 + o;
            float gco = mre[(pp - oc + 64) & 63] * A[oc] * (0.125f / 64.0f);
            val += gco * cw[(oc * 8 + cil) * 9 + sp];
        }
        int ks = c >> 4, lh = (c >> 3) & 1, e = c & 7;
        int lane = (lh << 5) | l31;
        g_Mf[((((sp << 2) + ks) * 2 + mh) << 9) + (lane << 3) + e] = f2bf(val);
    }
    if (p == 0 && t < 64)
        g_b2[t] = bias[perm[t]] * 0.125f;
}

// 256 blocks x 1024 thr (1/CU). Block = image x 12 full-width rows; 2-row steps,
// 6-slot circular window (LDS = x only, 149 KB). 12 COMPUTE waves (2 rows x 6
// 32px tiles, mfma_32x32x16, both m-halves; A from L2 via coalesced g_Mf frags,
// B from LDS: 1 ds_read per 2 A-gloads per 2 MFMA-32) + 4 STAGING waves
// (rows hb+3,hb+4 -> slots (2t+4..5)%6, disjoint from read slots (2t..2t+3)%6)
// -> ONE barrier per step. Cuts block LDS b128 reads 13.8K (R25) -> 2.6K.
__global__ __launch_bounds__(1024)
void acdc_main(const float* __restrict__ x, float* __restrict__ out) {
    __shared__ __align__(16) unsigned char xsb[6 * SLOTB];   // 148992 B

    int tid = threadIdx.x;
    int lane = tid & 63, wv = tid >> 6;
    // bijective XCD swizzle: each XCD gets 32 consecutive logical blocks = 2 images
    int Lb = (blockIdx.x & 7) * (NBLKS / 8) + (blockIdx.x >> 3);
    int bb = Lb >> 4;                 // image
    int h0 = (Lb & 15) * ROWS;        // row band; h0 % 12 == 0

    const float* xb = x + (size_t)bb * Cn * Hn * Wn;

    // ---- prologue: rows h0-1..h0+2 -> slots 0..3 (all 1024 threads) ----
    for (int k = 0; k < 7; ++k) {
        int idx = tid + (k << 10);
        if (idx >= 6400) break;
        int cp_lo = idx & 3;
        int f = (idx >> 2) % 50;
        int rest = idx / 200;             // 0..31
        int rr = rest & 3, cp_hi = rest >> 2;
        int cp = cp_hi * 4 + cp_lo;
        int gi = h0 - 1 + rr;
        float4 va = (float4){0.f,0.f,0.f,0.f}, vb = (float4){0.f,0.f,0.f,0.f};
        bool ok = (unsigned)gi < (unsigned)Hn;
        if (ok && f >= 1 && f <= 48) {
            const float* r0 = xb + ((size_t)(2 * cp) * Hn + gi) * Wn + (f * 4 - 4);
            va = *(const float4*)r0;
            vb = *(const float4*)(r0 + Hn * Wn);
        }
        int slot = rr;                    // (gi+1)%6 == rr
        int chunk = cp >> 2, sub = (cp & 3) * 4;
        float v0[4] = {va.x, va.y, va.z, va.w};
        float v1[4] = {vb.x, vb.y, vb.z, vb.w};
        #pragma unroll
        for (int j = 0; j < 4; ++j) {
            int c2 = f * 4 - 3 + j;
            if ((unsigned)c2 >= 194u) continue;
            unsigned u;
            asm("v_cvt_pk_bf16_f32 %0, %1, %2" : "=v"(u) : "v"(v0[j]), "v"(v1[j]));
            int key = (c2 + (c2 >> 3) + 3 * slot) & 7;
            *(unsigned*)(xsb + slot * SLOTB + c2 * 128 + ((chunk ^ key) << 4) + sub) = u;
        }
    }
    __syncthreads();   // window rows h0-1..h0+2 ready

    int l31 = lane & 31, lh = lane >> 5;

    for (int t = 0; t < 6; ++t) {
        int hb = h0 + 2 * t;

        if (wv < 12) {
            // ---- compute: wave = (row rr, 32px tile nt); both m-halves ----
            int rr = wv & 1;
            int nt = wv >> 1;            // 0..5
            f32x16 acc0, acc1;
            #pragma unroll
            for (int e = 0; e < 16; ++e) { acc0[e] = 0.f; acc1[e] = 0.f; }

            #pragma unroll
            for (int sp = 0; sp < 9; ++sp) {
                const int dy = sp / 3, dx = sp % 3;
                int v = 2 * t + rr + dy; if (v >= 6) v -= 6; if (v >= 6) v -= 6;
                int c2 = nt * 32 + l31 + dx;
                int key = (c2 + (c2 >> 3) + 3 * v) & 7;
                const unsigned char* bbase = xsb + v * SLOTB + c2 * 128;
                const unsigned char* afrag = (const unsigned char*)g_Mf + sp * 8192 + lane * 16;
                #pragma unroll
                for (int ks = 0; ks < 4; ++ks) {
                    int o = 2 * ks + lh;                   // k-octet
                    bf16x8 bfr = *(const bf16x8*)(bbase + ((o ^ key) << 4));
                    bf16x8 am0 = *(const bf16x8*)(afrag + ks * 2048);
                    bf16x8 am1 = *(const bf16x8*)(afrag + ks * 2048 + 1024);
                    __builtin_amdgcn_s_setprio(1);
                    acc0 = __builtin_amdgcn_mfma_f32_32x32x16_bf16(am0, bfr, acc0, 0, 0, 0);
                    acc1 = __builtin_amdgcn_mfma_f32_32x32x16_bf16(am1, bfr, acc1, 0, 0, 0);
                    __builtin_amdgcn_s_setprio(0);
                }
            }

            // ---- epilogue: +bias; C/D: ch = (r&3)+8*(r>>2)+4*lh, px = l31 ----
            int h = hb + rr;
            int pxg = nt * 32 + l31;
            #pragma unroll
            for (int r = 0; r < 16; ++r) {
                int chq = (r & 3) + 8 * (r >> 2) + 4 * lh;
                out[(((size_t)(bb * Cn + chq)) * Hn + h) * Wn + pxg]      = acc0[r] + g_b2[chq];
                out[(((size_t)(bb * Cn + 32 + chq)) * Hn + h) * Wn + pxg] = acc1[r] + g_b2[32 + chq];
            }
        } else if (t < 5) {
            // ---- staging waves (256 thr): rows hb+3, hb+4 -> slots (2t+4..5)%6 ----
            for (int k = 0; k < 13; ++k) {
                int sidx = (tid - 768) + (k << 8);
                if (sidx >= 3200) break;
                int cp_lo = sidx & 3;
                int f = (sidx >> 2) % 50;
                int rest = sidx / 200;        // 0..15
                int rr2 = rest & 1, cp_hi = rest >> 1;
                int cp = cp_hi * 4 + cp_lo;
                int gi = hb + 3 + rr2;
                float4 va = (float4){0.f,0.f,0.f,0.f}, vb = (float4){0.f,0.f,0.f,0.f};
                bool ok = (unsigned)gi < (unsigned)Hn;
                if (ok && f >= 1 && f <= 48) {
                    const float* r0 = xb + ((size_t)(2 * cp) * Hn + gi) * Wn + (f * 4 - 4);
                    va = *(const float4*)r0;
                    vb = *(const float4*)(r0 + Hn * Wn);
                }
                int vslot = 2 * t + 4 + rr2; if (vslot >= 6) vslot -= 6; if (vslot >= 6) vslot -= 6;
                int chunk = cp >> 2, sub = (cp & 3) * 4;
                float v0[4] = {va.x, va.y, va.z, va.w};
                float v1[4] = {vb.x, vb.y, vb.z, vb.w};
                #pragma unroll
                for (int j = 0; j < 4; ++j) {
                    int c2 = f * 4 - 3 + j;
                    if ((unsigned)c2 >= 194u) continue;
                    unsigned u;
                    asm("v_cvt_pk_bf16_f32 %0, %1, %2" : "=v"(u) : "v"(v0[j]), "v"(v1[j]));
                    int key = (c2 + (c2 >> 3) + 3 * vslot) & 7;
                    *(unsigned*)(xsb + vslot * SLOTB + c2 * 128 + ((chunk ^ key) << 4) + sub) = u;
                }
            }
        }

        __syncthreads();   // single barrier: publishes new rows, fences slot reuse
    }
}

extern "C" void kernel_launch(void* const* d_in, const int* in_sizes, int n_in,
                              void* d_out, int out_size, void* d_ws, size_t ws_size,
                              hipStream_t stream) {
    const float* x    = (const float*)d_in[0];
    const float* cw   = (const float*)d_in[1];
    const float* A    = (const float*)d_in[2];
    const float* D    = (const float*)d_in[3];
    const float* bias = (const float*)d_in[4];
    const int*   perm = (const int*)d_in[5];

    acdc_precompute<<<dim3(64), dim3(256), 0, stream>>>(cw, A, D, bias, perm);
    acdc_main<<<dim3(NBLKS), dim3(1024), 0, stream>>>(x, (float*)d_out);
}